// Round 4
// baseline (126.343 us; speedup 1.0000x reference)
//
#include <hip/hip_runtime.h>

// SparseConv1x1: out[b,r,hw] = sum_{k in row r} values[k] * in[b,col[k],hw]
// in/out: [8, 256, 3136] f32. nnz ~6553, CSR-sorted by row.
//
// R4: ELL-formatted sparse stream (built per-call in d_ws).
//  - prep_rows: per-row start/len + per-8-row-group padded loop bounds.
//  - prep_ell : column-major ELL, ell[j*256 + r] = (col*TQ, value_bits), 0-padded.
//  - main     : TQ=8 (32-pixel) LDS tile, 5 blocks/CU; wave-uniform j-loop,
//               one 64B line per ELL VMEM instr, x4 unroll, 4 acc chains.

#define HWQ    784   // 3136/4 float4-quads per (b,c) plane
#define CH     256
#define NF     256
#define TQ     8     // float4-quads per tile (32 pixels)
#define NTILE  98    // HWQ / TQ
#define ELLCAP 96    // padded row capacity (actual max len ~45, fixed dataset)

// d_ws layout (bytes):
//   int2 ell[ELLCAP*256]   @ 0        (196608)
//   int  start[256]        @ 196608
//   int  len[256]          @ 197632
//   int  gbound[32]        @ 198656   (per 8-row group, rounded up to x4)

__global__ __launch_bounds__(256) void prep_rows(
    const int* __restrict__ row_ids, int nnz,
    int* __restrict__ start, int* __restrict__ len, int* __restrict__ gbound)
{
    const int r = threadIdx.x;
    int lo = 0, hi = nnz;
    while (lo < hi) { int m = (lo + hi) >> 1; if (row_ids[m] < r)     lo = m + 1; else hi = m; }
    const int s = lo;
    hi = nnz;
    while (lo < hi) { int m = (lo + hi) >> 1; if (row_ids[m] < r + 1) lo = m + 1; else hi = m; }
    start[r] = s;
    const int L = lo - s;
    len[r] = L;

    __shared__ int sl[256];
    sl[r] = L;
    __syncthreads();
    if (r < 32) {
        int mx = 0;
        #pragma unroll
        for (int u = 0; u < 8; ++u) mx = max(mx, sl[r * 8 + u]);
        gbound[r] = (mx + 3) & ~3;   // assumed <= ELLCAP for this dataset
    }
}

__global__ __launch_bounds__(256) void prep_ell(
    const float* __restrict__ values, const int* __restrict__ col_ids,
    const int* __restrict__ start, const int* __restrict__ len,
    int2* __restrict__ ell)
{
    const int r = threadIdx.x;
    const int j = blockIdx.x;
    int2 e = make_int2(0, 0);
    if (j < len[r]) {
        const int k = start[r] + j;
        e = make_int2(col_ids[k] * TQ, __float_as_int(values[k]));
    }
    ell[j * 256 + r] = e;
}

__global__ __launch_bounds__(256, 5) void SparseConv1x1_kernel(
    const float4* __restrict__ in4,
    const int2*   __restrict__ ell,
    const int*    __restrict__ gbound,
    float4*       __restrict__ out4)
{
    __shared__ float4 tile[CH * TQ];     // 32 KB, layout [c][quad]

    const int t     = threadIdx.x;
    const int half  = blockIdx.x;        // 0/1: which 128 rows
    const int tl    = blockIdx.y;        // tile within image
    const int b     = blockIdx.z;
    const int qbase = tl * TQ;

    // Stage tile: 2048 float4s, 8 per thread, fully coalesced.
    #pragma unroll
    for (int i2 = 0; i2 < 8; ++i2) {
        const int idx = i2 * 256 + t;
        const int c   = idx >> 3;
        const int j   = idx & 7;
        tile[idx] = in4[((size_t)(b * CH + c)) * HWQ + qbase + j];
    }
    __syncthreads();

    const int q  = t & 7;                // quad within tile
    const int rg = t >> 3;               // row-group 0..31 (8 consecutive rows/wave-group)
    const int w  = rg >> 3;              // wave id 0..3

    // Preload the 4 wave-uniform loop bounds.
    int Lb[4];
    #pragma unroll
    for (int i = 0; i < 4; ++i) Lb[i] = gbound[half * 16 + i * 4 + w];

    #pragma unroll
    for (int i = 0; i < 4; ++i) {
        const int r = half * 128 + i * 32 + rg;
        const int L = Lb[i];
        const int2* __restrict__ ep = ell + r;   // ep[j*256] = ell[j*256 + r]

        float4 a0 = make_float4(0.f, 0.f, 0.f, 0.f);
        float4 a1 = make_float4(0.f, 0.f, 0.f, 0.f);
        float4 a2 = make_float4(0.f, 0.f, 0.f, 0.f);
        float4 a3 = make_float4(0.f, 0.f, 0.f, 0.f);

        for (int j = 0; j < L; j += 4) {         // L is a multiple of 4; padding is (0, 0.0f)
            const int2 p0 = ep[(j + 0) * 256];
            const int2 p1 = ep[(j + 1) * 256];
            const int2 p2 = ep[(j + 2) * 256];
            const int2 p3 = ep[(j + 3) * 256];
            const float4 x0 = tile[p0.x + q];
            const float4 x1 = tile[p1.x + q];
            const float4 x2 = tile[p2.x + q];
            const float4 x3 = tile[p3.x + q];
            const float v0 = __int_as_float(p0.y);
            const float v1 = __int_as_float(p1.y);
            const float v2 = __int_as_float(p2.y);
            const float v3 = __int_as_float(p3.y);
            a0.x = fmaf(v0, x0.x, a0.x); a0.y = fmaf(v0, x0.y, a0.y);
            a0.z = fmaf(v0, x0.z, a0.z); a0.w = fmaf(v0, x0.w, a0.w);
            a1.x = fmaf(v1, x1.x, a1.x); a1.y = fmaf(v1, x1.y, a1.y);
            a1.z = fmaf(v1, x1.z, a1.z); a1.w = fmaf(v1, x1.w, a1.w);
            a2.x = fmaf(v2, x2.x, a2.x); a2.y = fmaf(v2, x2.y, a2.y);
            a2.z = fmaf(v2, x2.z, a2.z); a2.w = fmaf(v2, x2.w, a2.w);
            a3.x = fmaf(v3, x3.x, a3.x); a3.y = fmaf(v3, x3.y, a3.y);
            a3.z = fmaf(v3, x3.z, a3.z); a3.w = fmaf(v3, x3.w, a3.w);
        }

        float4 acc;
        acc.x = (a0.x + a1.x) + (a2.x + a3.x);
        acc.y = (a0.y + a1.y) + (a2.y + a3.y);
        acc.z = (a0.z + a1.z) + (a2.z + a3.z);
        acc.w = (a0.w + a1.w) + (a2.w + a3.w);
        out4[((size_t)(b * NF + r)) * HWQ + qbase + q] = acc;
    }
}

extern "C" void kernel_launch(void* const* d_in, const int* in_sizes, int n_in,
                              void* d_out, int out_size, void* d_ws, size_t ws_size,
                              hipStream_t stream) {
    const float* inputs  = (const float*)d_in[0];
    const float* values  = (const float*)d_in[1];
    const int*   row_ids = (const int*)  d_in[2];
    const int*   col_ids = (const int*)  d_in[3];
    const int nnz = in_sizes[1];

    char* ws = (char*)d_ws;
    int2* ell    = (int2*)(ws);
    int*  start  = (int*) (ws + 196608);
    int*  len    = (int*) (ws + 197632);
    int*  gbound = (int*) (ws + 198656);

    prep_rows<<<1, dim3(256, 1, 1), 0, stream>>>(row_ids, nnz, start, len, gbound);
    prep_ell<<<ELLCAP, dim3(256, 1, 1), 0, stream>>>(values, col_ids, start, len, ell);

    dim3 grid(2, NTILE, 8);
    SparseConv1x1_kernel<<<grid, dim3(256, 1, 1), 0, stream>>>(
        (const float4*)inputs, ell, gbound, (float4*)d_out);
}

// Round 5
// 89.271 us; speedup vs baseline: 1.4153x; 1.4153x over previous
//
#include <hip/hip_runtime.h>

// SparseConv1x1 as a dense bf16 MFMA GEMM: out[256, 25088] = W[256,256] * X[256, 25088]
// W is 10% dense -> densify to bf16 (128 KB) in d_ws, pre-swizzled into
// v_mfma_f32_32x32x16_bf16 A-operand fragment order.
//
// Layouts (CDNA4 32x32x16, verified C/D from learn_hip m74/m101):
//   A[m][k]: lane = (m&31) + 32*((k>>3)&1), byte j = k&7 within lane's 8 bf16
//   B[k][n]: lane = (n&31) + 32*((k>>3)&1), byte j = k&7
//   C/D    : col n = lane&31, row m = (reg&3) + 8*(reg>>2) + 4*(lane>>5)
//
// Main kernel: block = (32-pixel tile, batch). 784 blocks, 256 threads (4 waves).
//  - Stage X[256 c][32 n] fp32 -> bf16 into LDS in B-fragment order (16 chunks
//    of 1 KB, conflict-free b128 writes/reads).
//  - Wave w computes rows w*64..w*64+63: 2 accumulators x 16 k-steps = 32 MFMAs.
//  - A-frags read straight from the swizzled W buffer (coalesced 1KB/instr, L2-hot).

#define HW    3136
#define CH    256
#define NF    256
#define NT    32            // pixels per tile
#define NTILE 98            // HW / NT

typedef __attribute__((ext_vector_type(8)))  short bf16x8;
typedef __attribute__((ext_vector_type(16))) float f32x16;

__device__ __forceinline__ unsigned rne_bf16(float f) {
    unsigned u = __float_as_uint(f);
    return (u + 0x7FFFu + ((u >> 16) & 1u)) >> 16;   // RNE to bf16, return low 16 bits
}

// Scatter CSR nonzeros into the swizzled dense bf16 W (zeroed beforehand).
__global__ __launch_bounds__(256) void w_scatter(
    const float* __restrict__ values,
    const int*   __restrict__ row_ids,
    const int*   __restrict__ col_ids,
    unsigned short* __restrict__ wsw,   // 128 chunks * 512 halfwords
    int nnz)
{
    int i = blockIdx.x * 256 + threadIdx.x;
    if (i >= nnz) return;
    const int m = row_ids[i];
    const int c = col_ids[i];
    const int chunk = (m >> 5) * 16 + (c >> 4);
    const int lane  = (m & 31) + 32 * ((c >> 3) & 1);
    wsw[chunk * 512 + lane * 8 + (c & 7)] = (unsigned short)rne_bf16(values[i]);
}

__global__ __launch_bounds__(256) void spmm_mfma(
    const float*  __restrict__ X,      // [8][256][3136]
    const bf16x8* __restrict__ wsw,    // swizzled W, [(mt*16+kt)*64 + lane]
    float*        __restrict__ out)    // [8][256][3136]
{
    __shared__ int4 ldsq[16 * 64];     // 16 KB: chunk kt, lane -> 8 bf16 of B-frag

    const int t  = threadIdx.x;
    const int l  = t & 63;
    const int w  = t >> 6;
    const int n0 = blockIdx.x * NT;
    const int b  = blockIdx.y;

    const float* __restrict__ Xb = X + (size_t)b * (CH * HW);

    // ---- Stage X tile into LDS in B-fragment order ----
    // Slot (kt, lane): k = kt*16 + (l>>5)*8 + j (j=0..7), n = n0 + (l&31).
    // Thread t fills 4 slots: kt = i*4 + (t>>6).
    #pragma unroll
    for (int i = 0; i < 4; ++i) {
        const int kt    = i * 4 + w;
        const int kbase = kt * 16 + (l >> 5) * 8;
        const float* __restrict__ p = Xb + (size_t)kbase * HW + n0 + (l & 31);
        unsigned r0 = rne_bf16(p[0 * HW]);
        unsigned r1 = rne_bf16(p[1 * HW]);
        unsigned r2 = rne_bf16(p[2 * HW]);
        unsigned r3 = rne_bf16(p[3 * HW]);
        unsigned r4 = rne_bf16(p[4 * HW]);
        unsigned r5 = rne_bf16(p[5 * HW]);
        unsigned r6 = rne_bf16(p[6 * HW]);
        unsigned r7 = rne_bf16(p[7 * HW]);
        int4 v;
        v.x = (int)(r0 | (r1 << 16));
        v.y = (int)(r2 | (r3 << 16));
        v.z = (int)(r4 | (r5 << 16));
        v.w = (int)(r6 | (r7 << 16));
        ldsq[kt * 64 + l] = v;          // lane-contiguous 16B: conflict-free
    }
    __syncthreads();

    // ---- MFMA: wave w owns rows w*64 .. w*64+63 (m-tiles 2w, 2w+1) ----
    const bf16x8* __restrict__ ldsv = (const bf16x8*)ldsq;
    const int mt0 = w * 2, mt1 = w * 2 + 1;

    f32x16 acc0, acc1;
    #pragma unroll
    for (int i = 0; i < 16; ++i) { acc0[i] = 0.f; acc1[i] = 0.f; }

    #pragma unroll
    for (int kt = 0; kt < 16; ++kt) {
        const bf16x8 bfrag = ldsv[kt * 64 + l];
        const bf16x8 a0 = wsw[(mt0 * 16 + kt) * 64 + l];
        const bf16x8 a1 = wsw[(mt1 * 16 + kt) * 64 + l];
        acc0 = __builtin_amdgcn_mfma_f32_32x32x16_bf16(a0, bfrag, acc0, 0, 0, 0);
        acc1 = __builtin_amdgcn_mfma_f32_32x32x16_bf16(a1, bfrag, acc1, 0, 0, 0);
    }

    // ---- Epilogue: C/D col = n0 + (l&31), row = (i&3) + 8*(i>>2) + 4*(l>>5) ----
    float* __restrict__ ob = out + (size_t)b * (NF * HW) + n0 + (l & 31);
    const int rbase0 = w * 64;
    const int rbase1 = w * 64 + 32;
    const int rl     = 4 * (l >> 5);
    #pragma unroll
    for (int i = 0; i < 16; ++i) {
        const int row = (i & 3) + 8 * (i >> 2) + rl;
        ob[(size_t)(rbase0 + row) * HW] = acc0[i];
        ob[(size_t)(rbase1 + row) * HW] = acc1[i];
    }
}

extern "C" void kernel_launch(void* const* d_in, const int* in_sizes, int n_in,
                              void* d_out, int out_size, void* d_ws, size_t ws_size,
                              hipStream_t stream) {
    const float* inputs  = (const float*)d_in[0];
    const float* values  = (const float*)d_in[1];
    const int*   row_ids = (const int*)  d_in[2];
    const int*   col_ids = (const int*)  d_in[3];
    const int nnz = in_sizes[1];

    unsigned short* wsw = (unsigned short*)d_ws;   // 128 KB swizzled dense bf16 W

    hipMemsetAsync(d_ws, 0, 128 * 1024, stream);
    w_scatter<<<(nnz + 255) / 256, dim3(256, 1, 1), 0, stream>>>(
        values, row_ids, col_ids, wsw, nnz);

    dim3 grid(NTILE, 8, 1);
    spmm_mfma<<<grid, dim3(256, 1, 1), 0, stream>>>(
        inputs, (const bf16x8*)d_ws, (float*)d_out);
}